// Round 4
// baseline (136.243 us; speedup 1.0000x reference)
//
#include <hip/hip_runtime.h>
#include <hip/hip_bf16.h>

// GMM NLL: N=524288 rows, P=16, G=8.
// R4: pure-VALU triangular quad, V streamed through the SCALAR pipe.
//   R1: LDS-broadcast V -> ds_read-issue-bound (48.5us == 51us model).
//   R2: MFMA+shfl -> latency-bound (MfmaUtil 3.4%).
//   R3: scalar V, 1 row/thread -> 51us, VALUBusy 41% (21us issue vs 9us
//       model): per-element overhead instrs + s_load waits at ~3 waves/SIMD.
//   R4 fixes: (a) 2 rows/thread -- each V scalar feeds 2 FMAs (halves
//   overhead/row, 2x chain ILP, halves waits/row); (b) readfirstlane-forced
//   uniform pointer so V loads are s_load; (c) V packed in exact consumption
//   order (row i: [-u_i, V_i0..V_ii], 152 floats/group) for sequential
//   s_load_dwordx16 streaming. Floor: ~1216 FMA/row -> ~9us; target 18-28us.

#define P 16
#define G 8
#define GF 160                        // floats per group (152 used, 64B-align)
#define WS_LC   (G * GF)              // 1280: lcoef[G]
#define WS_LAM  (WS_LC + G)
#define WS_LM1  (WS_LAM + P)
#define WS_RL   (WS_LM1 + P)
#define ROWS_PER_THREAD 2

__device__ __forceinline__ const float* uniform_ptr(const float* p) {
    union { const float* p; unsigned u[2]; } c;
    c.p = p;
    c.u[0] = __builtin_amdgcn_readfirstlane(c.u[0]);
    c.u[1] = __builtin_amdgcn_readfirstlane(c.u[1]);
    return c.p;
}

__global__ __launch_bounds__(128) void gmm_prep(const float* __restrict__ lambdas,
                                                const float* __restrict__ mus,
                                                const float* __restrict__ sigmas,
                                                const float* __restrict__ w,
                                                float* __restrict__ ws,
                                                float* __restrict__ out) {
    __shared__ float Lsh[G][P][P];
    __shared__ float Vsh[G][P][P];
    __shared__ float ldet[G];
    const int tid = threadIdx.x;
    const int g = tid >> 4;
    const int r = tid & 15;

    float Srow[P], Lrow[P];
#pragma unroll
    for (int j = 0; j < P; ++j) Srow[j] = sigmas[g * P * P + r * P + j];

#pragma unroll
    for (int j = 0; j < P; ++j) {
        float s = Srow[j];
#pragma unroll
        for (int k = 0; k < P; ++k) {
            if (k < j) s -= Lrow[k] * Lsh[g][j][k];
        }
        if (r == j) {
            float dv = sqrtf(s);
            Lrow[j] = dv;
            Lsh[g][j][j] = dv;
        }
        __syncthreads();
        if (r > j) {
            float dv = s / Lsh[g][j][j];
            Lrow[j] = dv;
            Lsh[g][r][j] = dv;
        }
        __syncthreads();
    }

    if (r == 0) {
        float ld = 0.f;
#pragma unroll
        for (int j = 0; j < P; ++j) ld += __logf(Lsh[g][j][j]);
        ldet[g] = 2.0f * ld;
    }

    // invert L: thread r computes column r of V = L^{-1}
    float col[P];
#pragma unroll
    for (int i = 0; i < P; ++i) {
        float s = 0.f;
#pragma unroll
        for (int k = 0; k < P; ++k) {
            if (k < i) s += Lsh[g][i][k] * col[k];
        }
        float rii = 1.0f / Lsh[g][i][i];
        col[i] = (i == r) ? rii : -s * rii;
    }
#pragma unroll
    for (int i = 0; i < P; ++i) Vsh[g][i][r] = col[i];
    __syncthreads();

    // u_g[r] = (V_g mu_g)[r]
    float u = 0.f;
#pragma unroll
    for (int j = 0; j < P; ++j) u = fmaf(Vsh[g][r][j], mus[g * P + j], u);

    // packed stream, consumption order: row r at base = r + r(r+1)/2:
    //   [-u_r, V_r0 .. V_rr]
    {
        float* Wg = ws + g * GF;
        const int base = r + (r * (r + 1)) / 2;
        Wg[base] = -u;
#pragma unroll
        for (int j = 0; j < P; ++j)
            if (j <= r) Wg[base + 1 + j] = Vsh[g][r][j];
    }

    if (tid == 0) {
        float wm = w[0];
#pragma unroll
        for (int k = 1; k < G; ++k) wm = fmaxf(wm, w[k]);
        float s = 0.f;
#pragma unroll
        for (int k = 0; k < G; ++k) s += __expf(w[k] - wm);
        const float lse = wm + __logf(s);
        const float lead = -14.7030165f; // -0.5 * 16 * ln(2*pi)
#pragma unroll
        for (int k = 0; k < G; ++k)
            ws[WS_LC + k] = (w[k] - lse) + lead - 0.5f * ldet[k];
        out[0] = 0.f;
    }
    if (tid < P) {
        float lam = lambdas[tid];
        ws[WS_LAM + tid] = lam;
        ws[WS_LM1 + tid] = lam - 1.0f;
        ws[WS_RL  + tid] = 1.0f / lam;
    }
}

__global__ __launch_bounds__(256, 4) void gmm_main(const float* __restrict__ X,
                                                   const float* __restrict__ ws,
                                                   float* __restrict__ out,
                                                   int nrows) {
    __shared__ float red[4];

    const int tid  = threadIdx.x;
    const int lane = tid & 63;
    const int wid  = tid >> 6;

    const int row0 = blockIdx.x * (256 * ROWS_PER_THREAD) + tid;
    const int row1 = row0 + 256;
    const int rc0 = row0 < nrows ? row0 : nrows - 1;
    const int rc1 = row1 < nrows ? row1 : nrows - 1;

    const float* wsu = uniform_ptr(ws);

    float xt0[P], xt1[P];
    float jac0 = 0.f, jac1 = 0.f;
    {
        const float4* Xv0 = (const float4*)(X + (size_t)rc0 * P);
        const float4* Xv1 = (const float4*)(X + (size_t)rc1 * P);
        float4 a0 = Xv0[0], a1 = Xv0[1], a2 = Xv0[2], a3 = Xv0[3];
        float4 b0 = Xv1[0], b1 = Xv1[1], b2 = Xv1[2], b3 = Xv1[3];
        float x0[P] = {a0.x, a0.y, a0.z, a0.w, a1.x, a1.y, a1.z, a1.w,
                       a2.x, a2.y, a2.z, a2.w, a3.x, a3.y, a3.z, a3.w};
        float x1[P] = {b0.x, b0.y, b0.z, b0.w, b1.x, b1.y, b1.z, b1.w,
                       b2.x, b2.y, b2.z, b2.w, b3.x, b3.y, b3.z, b3.w};
#pragma unroll
        for (int p = 0; p < P; ++p) {
            const float lam = wsu[WS_LAM + p];
            const float lm1 = wsu[WS_LM1 + p];
            const float rl  = wsu[WS_RL + p];
            float ln0 = __logf(x0[p]);
            float ln1 = __logf(x1[p]);
            xt0[p] = (__expf(lam * ln0) - 1.0f) * rl;
            xt1[p] = (__expf(lam * ln1) - 1.0f) * rl;
            jac0 = fmaf(ln0, lm1, jac0);
            jac1 = fmaf(ln1, lm1, jac1);
        }
    }

    float mixed0 = 0.f, mixed1 = 0.f;
#pragma unroll
    for (int g = 0; g < G; ++g) {
        const float* __restrict__ Vg = uniform_ptr(ws + g * GF);
        float quad0 = 0.f, quad1 = 0.f;
        int off = 0;
#pragma unroll
        for (int i = 0; i < P; ++i) {
            float y0 = Vg[off];          // -u_i (scalar -> broadcast)
            float y1 = y0;
            ++off;
#pragma unroll
            for (int j = 0; j <= i; ++j, ++off) {
                const float v = Vg[off]; // sequential scalar stream
                y0 = fmaf(v, xt0[j], y0);
                y1 = fmaf(v, xt1[j], y1);
            }
            quad0 = fmaf(y0, y0, quad0);
            quad1 = fmaf(y1, y1, quad1);
        }
        const float lc = wsu[WS_LC + g];
        mixed0 += __expf(fmaf(-0.5f, quad0, lc + jac0));
        mixed1 += __expf(fmaf(-0.5f, quad1, lc + jac1));
    }

    float nll = 0.f;
    if (row0 < nrows) nll -= __logf(mixed0);
    if (row1 < nrows) nll -= __logf(mixed1);

#pragma unroll
    for (int off = 32; off > 0; off >>= 1) nll += __shfl_down(nll, off, 64);
    if (lane == 0) red[wid] = nll;
    __syncthreads();
    if (tid == 0) atomicAdd(out, red[0] + red[1] + red[2] + red[3]);
}

extern "C" void kernel_launch(void* const* d_in, const int* in_sizes, int n_in,
                              void* d_out, int out_size, void* d_ws, size_t ws_size,
                              hipStream_t stream) {
    const float* X       = (const float*)d_in[0];
    const float* lambdas = (const float*)d_in[1];
    const float* mus     = (const float*)d_in[2];
    const float* sigmas  = (const float*)d_in[3];
    const float* w       = (const float*)d_in[4];
    float* out = (float*)d_out;
    float* ws  = (float*)d_ws;

    const int nrows = in_sizes[0] / P;   // 524288

    gmm_prep<<<1, 128, 0, stream>>>(lambdas, mus, sigmas, w, ws, out);
    const int rows_per_block = 256 * ROWS_PER_THREAD;
    gmm_main<<<(nrows + rows_per_block - 1) / rows_per_block, 256, 0, stream>>>(
        X, ws, out, nrows);
}

// Round 5
// 113.043 us; speedup vs baseline: 1.2052x; 1.2052x over previous
//
#include <hip/hip_runtime.h>
#include <hip/hip_bf16.h>

// GMM NLL: N=524288 rows, P=16, G=8.
// R5: 32x32x16 bf16 MFMA, zero-waste tiling.
//   R1 LDS-broadcast: ds-issue bound 48.5us. R2 16x16 MFMA: 4x wasted MFMA +
//   64 shfl/wave, latency-bound 44us. R3/R4 scalar-pipe: LLVM never emits the
//   clean s_load+v_fmac stream; 51-60us, spills in R4.
//   R5: per MFMA pair p: A=[V_2p;V_2p+1] (32x16, K=16=P exactly),
//   B = xt for 32 data rows (one ds_read_b128/lane). -u via chained init
//   MFMA (A = -u column, B = ones). quad = per-lane 8-square partial +
//   one xor-32 exchange (asymmetric keep/send: 4 shfl + 1 for mixed).
//   Per wave/64 rows: 16 MFMA + ~14 ds + 10 shfl vs R1's 320 ds.

#define P 16
#define G 8

typedef short bf16x8 __attribute__((ext_vector_type(8)));
typedef float f32x16 __attribute__((ext_vector_type(16)));

__device__ __forceinline__ unsigned short f2bf(float f) {
    union { float f; unsigned u; } c; c.f = f;
    unsigned u = c.u;
    return (unsigned short)((u + 0x7FFFu + ((u >> 16) & 1u)) >> 16);  // RNE
}

// ws float-offset layout:
//   [0,1024)    A-frags: ushort[4 pairs][64 lanes][8]  (4 KB)
//   [1024,1280) u-frags: uint[4 pairs][64 lanes] (low16 = bf16(-u), 0 for lane>=32)
//   [1280,1288) lcoef[G] = log softmax(w) + lead - 0.5*logdet
//   [1288,...)  lam[P], lam-1[P], 1/lam[P]
#define UFRAG_F 1024
#define WS_LC   1280
#define WS_LAM  1288
#define WS_LM1  1304
#define WS_RL   1320

__global__ __launch_bounds__(128) void gmm_prep(const float* __restrict__ lambdas,
                                                const float* __restrict__ mus,
                                                const float* __restrict__ sigmas,
                                                const float* __restrict__ w,
                                                float* __restrict__ ws,
                                                float* __restrict__ out) {
    __shared__ float Lsh[G][P][P];
    __shared__ float Vsh[G][P][P];
    __shared__ float u_sh[G][P];
    __shared__ float ldet[G];
    const int tid = threadIdx.x;
    const int g = tid >> 4;
    const int r = tid & 15;

    float Srow[P], Lrow[P];
#pragma unroll
    for (int j = 0; j < P; ++j) Srow[j] = sigmas[g * P * P + r * P + j];

#pragma unroll
    for (int j = 0; j < P; ++j) {
        float s = Srow[j];
#pragma unroll
        for (int k = 0; k < P; ++k) {
            if (k < j) s -= Lrow[k] * Lsh[g][j][k];
        }
        if (r == j) {
            float dv = sqrtf(s);
            Lrow[j] = dv;
            Lsh[g][j][j] = dv;
        }
        __syncthreads();
        if (r > j) {
            float dv = s / Lsh[g][j][j];
            Lrow[j] = dv;
            Lsh[g][r][j] = dv;
        }
        __syncthreads();
    }

    if (r == 0) {
        float ld = 0.f;
#pragma unroll
        for (int j = 0; j < P; ++j) ld += __logf(Lsh[g][j][j]);
        ldet[g] = 2.0f * ld;
    }

    // invert L: thread r computes column r of V = L^{-1}
    float col[P];
#pragma unroll
    for (int i = 0; i < P; ++i) {
        float s = 0.f;
#pragma unroll
        for (int k = 0; k < P; ++k) {
            if (k < i) s += Lsh[g][i][k] * col[k];
        }
        float rii = 1.0f / Lsh[g][i][i];
        col[i] = (i == r) ? rii : -s * rii;
    }
#pragma unroll
    for (int i = 0; i < P; ++i) Vsh[g][i][r] = col[i];
    __syncthreads();

    // u_g[r] = (V_g mu_g)[r]
    {
        float u = 0.f;
#pragma unroll
        for (int j = 0; j < P; ++j) u = fmaf(Vsh[g][r][j], mus[g * P + j], u);
        u_sh[g][r] = u;
    }
    __syncthreads();

    // A/u fragment tables for mfma_f32_32x32x16_bf16:
    //   A[m][k], m=lane&31, k=(lane>>5)*8+j. Pair p rows: m<16 -> grp 2p, else 2p+1.
    unsigned short* ws16 = (unsigned short*)ws;
    unsigned* wsu32 = (unsigned*)(ws + UFRAG_F);
    for (int pid = tid; pid < 256; pid += 128) {
        const int p = pid >> 6, ln = pid & 63;
        const int m = ln & 31, half = ln >> 5;
        const int grp = 2 * p + (m >> 4), i = m & 15;
        unsigned short* dst = ws16 + (p * 64 + ln) * 8;
#pragma unroll
        for (int j = 0; j < 8; ++j) dst[j] = f2bf(Vsh[grp][i][half * 8 + j]);
        wsu32[p * 64 + ln] = (half == 0) ? (unsigned)f2bf(-u_sh[grp][i]) : 0u;
    }

    if (tid == 0) {
        float wm = w[0];
#pragma unroll
        for (int k = 1; k < G; ++k) wm = fmaxf(wm, w[k]);
        float s = 0.f;
#pragma unroll
        for (int k = 0; k < G; ++k) s += __expf(w[k] - wm);
        const float lse = wm + __logf(s);
        const float lead = -14.7030165f; // -0.5 * 16 * ln(2*pi)
#pragma unroll
        for (int k = 0; k < G; ++k)
            ws[WS_LC + k] = (w[k] - lse) + lead - 0.5f * ldet[k];
        out[0] = 0.f;
    }
    if (tid < P) {
        float lam = lambdas[tid];
        ws[WS_LAM + tid] = lam;
        ws[WS_LM1 + tid] = lam - 1.0f;
        ws[WS_RL  + tid] = 1.0f / lam;
    }
}

__global__ __launch_bounds__(256, 4) void gmm_main(const float* __restrict__ X,
                                                   const float* __restrict__ ws,
                                                   float* __restrict__ out,
                                                   int nrows) {
    __shared__ __align__(16) unsigned short sxt[8 * 64 * 8];  // 8 frag-slots x 64 lanes x 8 bf16
    __shared__ float red[4];

    const int tid  = threadIdx.x;
    const int lane = tid & 63;
    const int wid  = tid >> 6;
    const unsigned short* ws16 = (const unsigned short*)ws;

    // resident fragments: 4 pairs x (A: 4 VGPRs, u: 1 VGPR)
    bf16x8 av[4];
    unsigned uf[4];
#pragma unroll
    for (int p = 0; p < 4; ++p) {
        av[p] = *(const bf16x8*)(ws16 + (p * 64 + lane) * 8);
        uf[p] = ((const unsigned*)(ws + UFRAG_F))[p * 64 + lane];
    }
    float lcv[G];
#pragma unroll
    for (int k = 0; k < G; ++k) lcv[k] = ws[WS_LC + k];

    const int row = blockIdx.x * 256 + tid;
    const int rc = row < nrows ? row : nrows - 1;
    const float4* Xv = (const float4*)(X + (size_t)rc * P);
    float4 a0 = Xv[0], a1 = Xv[1], a2 = Xv[2], a3 = Xv[3];
    float xv[P] = {a0.x, a0.y, a0.z, a0.w, a1.x, a1.y, a1.z, a1.w,
                   a2.x, a2.y, a2.z, a2.w, a3.x, a3.y, a3.z, a3.w};

    float xt[P];
    float jac = 0.f;
#pragma unroll
    for (int p = 0; p < P; ++p) {
        float ln = __logf(xv[p]);
        xt[p] = (__expf(ws[WS_LAM + p] * ln) - 1.0f) * ws[WS_RL + p];
        jac = fmaf(ln, ws[WS_LM1 + p], jac);
    }

    // stage xt as B-fragments: frag slot F = tid>>5 (= wave*2 + tile),
    // entry F*64 + half*32 + (tid&31) holds xt[half*8 .. half*8+7]
    {
        unsigned xw[8];
#pragma unroll
        for (int h = 0; h < 8; ++h)
            xw[h] = (unsigned)f2bf(xt[2 * h]) | ((unsigned)f2bf(xt[2 * h + 1]) << 16);
        uint4* sv = (uint4*)sxt;
        const int F = tid >> 5, c = tid & 31;
        sv[F * 64 + c]      = make_uint4(xw[0], xw[1], xw[2], xw[3]);
        sv[F * 64 + 32 + c] = make_uint4(xw[4], xw[5], xw[6], xw[7]);
    }
    __syncthreads();

    // B1 frag (ones column for the -u init MFMA): B1[k][n] = (k==0)
    bf16x8 b1;
    {
        union { unsigned u[4]; bf16x8 v; } c;
        c.u[0] = (lane < 32) ? 0x00003F80u : 0u;  // bf16(1.0) at j=0 (k = (lane>>5)*8)
        c.u[1] = 0u; c.u[2] = 0u; c.u[3] = 0u;
        b1 = c.v;
    }
    const bool h = (lane >= 32);

    float nll = 0.f;
#pragma unroll
    for (int t = 0; t < 2; ++t) {
        const bf16x8 bx = *(const bf16x8*)(sxt + ((wid * 2 + t) * 64 + lane) * 8);
        const float jn = __shfl(jac, t * 32 + (lane & 31), 64);

        float pa[4], pb[4];
#pragma unroll
        for (int p = 0; p < 4; ++p) {
            union { unsigned u[4]; bf16x8 v; } auf;
            auf.u[0] = uf[p]; auf.u[1] = 0u; auf.u[2] = 0u; auf.u[3] = 0u;
            f32x16 acc = {};
            acc = __builtin_amdgcn_mfma_f32_32x32x16_bf16(auf.v, b1, acc, 0, 0, 0);
            acc = __builtin_amdgcn_mfma_f32_32x32x16_bf16(av[p], bx, acc, 0, 0, 0);
            // regs 0..7 -> group 2p (i-rows {0-3,8-11}+4h), regs 8..15 -> group 2p+1
            float sa = acc[0] * acc[0], sb = acc[8] * acc[8];
#pragma unroll
            for (int rg = 1; rg < 8; ++rg) {
                sa = fmaf(acc[rg], acc[rg], sa);
                sb = fmaf(acc[rg + 8], acc[rg + 8], sb);
            }
            pa[p] = sa; pb[p] = sb;
        }

        // asymmetric exchange: each lane keeps partials for its 4 exp-groups
        // and sends the partner's 4. q_j = keep_j + shfl_xor(send_j, 32).
        float keep[4], send[4];
        keep[0] = h ? pa[2] : pa[0];  send[0] = h ? pa[0] : pa[2];
        keep[1] = h ? pb[2] : pb[0];  send[1] = h ? pb[0] : pb[2];
        keep[2] = h ? pa[3] : pa[1];  send[2] = h ? pa[1] : pa[3];
        keep[3] = h ? pb[3] : pb[1];  send[3] = h ? pb[1] : pb[3];

        float m = 0.f;
#pragma unroll
        for (int j = 0; j < 4; ++j) {
            const float q = keep[j] + __shfl_xor(send[j], 32, 64);
            const float lc = h ? lcv[4 + j] : lcv[j];
            m += __expf(fmaf(-0.5f, q, lc + jn));
        }
        m += __shfl_xor(m, 32, 64);

        const int drow = blockIdx.x * 256 + wid * 64 + t * 32 + (lane & 31);
        if (!h && drow < nrows) nll -= __logf(m);
    }

#pragma unroll
    for (int off = 32; off > 0; off >>= 1) nll += __shfl_down(nll, off, 64);
    if (lane == 0) red[wid] = nll;
    __syncthreads();
    if (tid == 0) atomicAdd(out, red[0] + red[1] + red[2] + red[3]);
}

extern "C" void kernel_launch(void* const* d_in, const int* in_sizes, int n_in,
                              void* d_out, int out_size, void* d_ws, size_t ws_size,
                              hipStream_t stream) {
    const float* X       = (const float*)d_in[0];
    const float* lambdas = (const float*)d_in[1];
    const float* mus     = (const float*)d_in[2];
    const float* sigmas  = (const float*)d_in[3];
    const float* w       = (const float*)d_in[4];
    float* out = (float*)d_out;
    float* ws  = (float*)d_ws;

    const int nrows = in_sizes[0] / P;   // 524288

    gmm_prep<<<1, 128, 0, stream>>>(lambdas, mus, sigmas, w, ws, out);
    gmm_main<<<(nrows + 255) / 256, 256, 0, stream>>>(X, ws, out, nrows);
}